// Round 1
// baseline (639.660 us; speedup 1.0000x reference)
//
#include <hip/hip_runtime.h>

// Bidirectional RNN (H=20, input=1), B=4096, T=2048.
// Layout: one chain (seq, direction) per 4-lane DPP quad; lane j of the quad
// owns h[5j..5j+4] and the matching 5 rows of W_hh (100 VGPRs of weights).
// Cross-lane h broadcast via v_mov_dpp quad_perm (VALU pipe, no LDS).
// 512 blocks x 64 threads = 512 waves, 16 chains/wave.

static constexpr int TT = 2048;   // sequence length
static constexpr int BB = 4096;   // batch

// DPP helper: all args to update_dpp must be ICE -> macros with literal ctrl.
#define QB(v, CTRL) __builtin_bit_cast(float, __builtin_amdgcn_update_dpp( \
    0, __builtin_bit_cast(int, (v)), (CTRL), 0xF, 0xF, true))
// broadcast lane L (0..3) of each quad to the whole quad
#define BCAST_Q(v, L) QB((v), (L) * 0x55)
// quad_perm [1,0,3,2] (xor-1, involution) and [2,3,0,1] (xor-2, involution)
#define QXOR1(v) QB((v), 0xB1)
#define QXOR2(v) QB((v), 0x4E)

__device__ __forceinline__ float fast_tanh(float a) {
  // tanh(a) = sign(a) * (1-u)/(1+u), u = exp(-2|a|)  -- overflow-safe
  float u = __expf(-2.0f * __builtin_fabsf(a));
  float r = __builtin_amdgcn_rcpf(1.0f + u);
  float m = (1.0f - u) * r;
  return __builtin_copysignf(m, a);
}

// One recurrence step. L/E select which quad lane / float2 element holds x_t.
#define MV(JP)                                                               \
  do {                                                                       \
    _Pragma("unroll") for (int m = 0; m < 5; ++m) {                          \
      float hb = BCAST_Q(h[m], JP);                                          \
      _Pragma("unroll") for (int i = 0; i < 5; ++i)                          \
          acc[i] = __builtin_fmaf(hb, w[i][5 * (JP) + m], acc[i]);           \
    }                                                                        \
  } while (0)

#define STEP(L, E)                                                           \
  do {                                                                       \
    float xv = BCAST_Q(((E) ? xc.y : xc.x), L);                              \
    float acc[5];                                                            \
    _Pragma("unroll") for (int i = 0; i < 5; ++i)                            \
        acc[i] = __builtin_fmaf(xv, wih[i], bc[i]);                          \
    MV(0); MV(1); MV(2); MV(3);                                              \
    _Pragma("unroll") for (int i = 0; i < 5; ++i) h[i] = fast_tanh(acc[i]);  \
  } while (0)

__global__ __launch_bounds__(64, 2) void rnn_bidir_kernel(
    const float* __restrict__ x,
    const float* __restrict__ Wih_f, const float* __restrict__ Whh_f,
    const float* __restrict__ bih_f, const float* __restrict__ bhh_f,
    const float* __restrict__ Wih_b, const float* __restrict__ Whh_b,
    const float* __restrict__ bih_b, const float* __restrict__ bhh_b,
    const float* __restrict__ Wfc, const float* __restrict__ bfc,
    float* __restrict__ out) {
  const int tid = threadIdx.x;
  const int q = tid >> 2;  // quad index 0..15 (chain within wave)
  const int j = tid & 3;   // lane within quad: owns h[5j..5j+4]
  const int d = (blockIdx.x >= 256) ? 1 : 0;  // 0=fwd, 1=bwd (wave-uniform)
  const int blk = blockIdx.x & 255;
  const int b = blk * 16 + q;  // sequence index 0..4095

  const float* Wih = d ? Wih_b : Wih_f;
  const float* Whh = d ? Whh_b : Whh_f;
  const float* bih = d ? bih_b : bih_f;
  const float* bhh = d ? bhh_b : bhh_f;

  // Per-lane recurrent weights: rows 5j..5j+4 of W_hh (row-major 20x20).
  // Byte offset of a row = 80*(5j+r), always 16B aligned -> float4 loads.
  float w[5][20];
#pragma unroll
  for (int r = 0; r < 5; ++r) {
    const float4* src = reinterpret_cast<const float4*>(Whh + (5 * j + r) * 20);
#pragma unroll
    for (int c4 = 0; c4 < 5; ++c4) {
      float4 v = src[c4];
      w[r][c4 * 4 + 0] = v.x;
      w[r][c4 * 4 + 1] = v.y;
      w[r][c4 * 4 + 2] = v.z;
      w[r][c4 * 4 + 3] = v.w;
    }
  }
  float wih[5], bc[5], wfc[5];
#pragma unroll
  for (int m = 0; m < 5; ++m) {
    int hrow = 5 * j + m;
    wih[m] = Wih[hrow];
    bc[m] = bih[hrow] + bhh[hrow];
    // hn.view(-1,40) pairs consecutive batch rows: even b -> W_fc[0:20],
    // odd b -> W_fc[20:40]. b parity == q parity.
    wfc[m] = Wfc[(q & 1) * 20 + hrow];
  }

  const float* xrow = x + (size_t)b * TT;
  float h[5] = {0.f, 0.f, 0.f, 0.f, 0.f};

  // x prefetch: each lane holds 2 of the 8 upcoming x values.
  // fwd:  lane j holds t = s8+2j, s8+2j+1     (elem E -> t = s8+2j+E)
  // bwd:  lane j loads float2 at (TT-2-s8-2j) and swaps .x/.y so that
  //       elem E -> t = TT-1-s8-2j-E; consumption order is then identical.
  auto xload = [&](int s8) -> float2 {
    int base = d ? (TT - 2 - s8 - 2 * j) : (s8 + 2 * j);
    float2 v = *reinterpret_cast<const float2*>(xrow + base);
    if (d) {
      float t = v.x; v.x = v.y; v.y = t;
    }
    return v;
  };

  float2 xc = xload(0);
  for (int s8 = 0; s8 < TT; s8 += 8) {
    float2 xn = xc;
    if (s8 + 8 < TT) xn = xload(s8 + 8);  // prefetch next 8 steps
    STEP(0, 0); STEP(0, 1);
    STEP(1, 0); STEP(1, 1);
    STEP(2, 0); STEP(2, 1);
    STEP(3, 0); STEP(3, 1);
    xc = xn;
  }

  // Epilogue: out[row] = W_fc[0:20].h(even b) + W_fc[20:40].h(odd b) + b_fc
  // row = d*2048 + b/2. Chains 2k,2k+1 are quads q,q+1 (same 16-lane DPP row).
  float p = 0.f;
#pragma unroll
  for (int m = 0; m < 5; ++m) p = __builtin_fmaf(wfc[m], h[m], p);
  p += QXOR1(p);  // sum lane pairs within quad
  p += QXOR2(p);  // full quad sum in all 4 lanes
  // add partner quad's sum: lane ^ 4 via ds_swizzle bit-mode (xor=4)
  float pn = __builtin_bit_cast(
      float, __builtin_amdgcn_ds_swizzle(__builtin_bit_cast(int, p), 0x101F));
  float tot = p + pn;  // valid on every lane of each quad pair
  if ((tid & 7) == 0) {
    int oidx = d * (BB / 2) + blk * 8 + (tid >> 3);
    out[oidx] = tot + bfc[0];
  }
}

extern "C" void kernel_launch(void* const* d_in, const int* in_sizes, int n_in,
                              void* d_out, int out_size, void* d_ws,
                              size_t ws_size, hipStream_t stream) {
  (void)in_sizes; (void)n_in; (void)d_ws; (void)ws_size; (void)out_size;
  const float* x     = (const float*)d_in[0];
  const float* Wih_f = (const float*)d_in[1];
  const float* Whh_f = (const float*)d_in[2];
  const float* bih_f = (const float*)d_in[3];
  const float* bhh_f = (const float*)d_in[4];
  const float* Wih_b = (const float*)d_in[5];
  const float* Whh_b = (const float*)d_in[6];
  const float* bih_b = (const float*)d_in[7];
  const float* bhh_b = (const float*)d_in[8];
  const float* Wfc   = (const float*)d_in[9];
  const float* bfc   = (const float*)d_in[10];
  float* out = (float*)d_out;

  // 256 fwd blocks + 256 bwd blocks, 1 wave each (16 chains/wave).
  hipLaunchKernelGGL(rnn_bidir_kernel, dim3(512), dim3(64), 0, stream,
                     x, Wih_f, Whh_f, bih_f, bhh_f,
                     Wih_b, Whh_b, bih_b, bhh_b, Wfc, bfc, out);
}

// Round 2
// 407.280 us; speedup vs baseline: 1.5706x; 1.5706x over previous
//
#include <hip/hip_runtime.h>

// Bidirectional RNN (H=20, input=1), B=4096, T=2048.
// One chain per 4-lane DPP quad; lane j owns h rows 5j..5j+4.
// Matvec in v_dot2_f32_f16 (fp16 pairs, fp32 accumulate): 50 dot2/step/wave
// instead of 100 fma; h broadcast as packed fp16 pairs: 10 DPP instead of 20.
// W_hh quantized once (RNE). h quantized per step via cvt_pkrtz with a
// (1+2^-11) pre-scale folded into tanh's final fma to cancel RTZ bias;
// the inverse scale is folded into the epilogue fma. Everything else fp32.

static constexpr int TT = 2048;   // sequence length
static constexpr int BB = 4096;   // batch

using half2v = decltype(__builtin_amdgcn_cvt_pkrtz(0.0f, 0.0f));

// DPP helpers (ctrl must be a literal -> macros).
#define QBI(v, CTRL) __builtin_amdgcn_update_dpp(0, (v), (CTRL), 0xF, 0xF, true)
#define QBF(v, CTRL) __builtin_bit_cast(float, QBI(__builtin_bit_cast(int, (v)), (CTRL)))
#define QBH(v, CTRL) __builtin_bit_cast(half2v, QBI(__builtin_bit_cast(int, (v)), (CTRL)))
#define BCAST_F(v, L) QBF((v), (L) * 0x55)   // bcast quad lane L (fp32)
#define BCAST_H(v, L) QBH((v), (L) * 0x55)   // bcast quad lane L (packed f16x2)
#define QXOR1_F(v) QBF((v), 0xB1)            // quad_perm [1,0,3,2]
#define QXOR2_F(v) QBF((v), 0x4E)            // quad_perm [2,3,0,1]

#if defined(__has_builtin) && __has_builtin(__builtin_amdgcn_fdot2)
#define FDOT2(a, b, c) __builtin_amdgcn_fdot2((a), (b), (c), false)
#else
#define FDOT2(a, b, c) \
  ((c) + (float)(a)[0] * (float)(b)[0] + (float)(a)[1] * (float)(b)[1])
#endif

__device__ __forceinline__ half2v mk_h2(float a, float b) {
  half2v t{};
  t[0] = a;  // RNE float->fp16
  t[1] = b;
  return t;
}

// tanh with (1+2^-11) output pre-scale (cancels cvt_pkrtz RTZ bias):
//   h = S * (1 - 2/(1 + e^{2a})),  S = 1.00048828125
// a -> +inf: u=inf, r=0, h=S.  a -> -inf: u=0, r=1, h=-S.  NaN-free.
__device__ __forceinline__ float tanh_scaled(float a) {
  float u = __builtin_amdgcn_exp2f(a * 2.8853900817779268f);  // e^{2a}
  float r = __builtin_amdgcn_rcpf(1.0f + u);
  return __builtin_fmaf(-2.0009765625f, r, 1.00048828125f);
}

// One recurrence step. L = quad lane holding x_t, E = float2 element.
// Packed-h broadcast slots (10), k-pair per slot:
//  s0(0,1) s1(2,3) s2(4,9) s3(5,6) s4(7,8)
//  s5(10,11) s6(12,13) s7(14,19) s8(15,16) s9(17,18)
#define STEP(L, E)                                                          \
  do {                                                                      \
    float xv = BCAST_F(((E) ? xc.y : xc.x), L);                             \
    float acc[5];                                                           \
    _Pragma("unroll") for (int i = 0; i < 5; ++i)                           \
        acc[i] = __builtin_fmaf(xv, wih[i], bc[i]);                         \
    half2v hb[10];                                                          \
    hb[0] = BCAST_H(pka, 0); hb[1] = BCAST_H(pkb, 0);                       \
    hb[2] = BCAST_H(pkc, 0);                                                \
    hb[3] = BCAST_H(pka, 1); hb[4] = BCAST_H(pkb, 1);                       \
    hb[5] = BCAST_H(pka, 2); hb[6] = BCAST_H(pkb, 2);                       \
    hb[7] = BCAST_H(pkc, 2);                                                \
    hb[8] = BCAST_H(pka, 3); hb[9] = BCAST_H(pkb, 3);                       \
    _Pragma("unroll") for (int s = 0; s < 10; ++s)                          \
      _Pragma("unroll") for (int i = 0; i < 5; ++i)                         \
          acc[i] = FDOT2(hb[s], wpk[i][s], acc[i]);                         \
    _Pragma("unroll") for (int i = 0; i < 5; ++i) h[i] = tanh_scaled(acc[i]); \
    float d4 = QXOR1_F(h[4]);                                               \
    pka = __builtin_amdgcn_cvt_pkrtz(h[0], h[1]);                           \
    pkb = __builtin_amdgcn_cvt_pkrtz(h[2], h[3]);                           \
    pkc = __builtin_amdgcn_cvt_pkrtz(h[4], d4);                             \
  } while (0)

__global__ __launch_bounds__(64, 2) void rnn_bidir_kernel(
    const float* __restrict__ x,
    const float* __restrict__ Wih_f, const float* __restrict__ Whh_f,
    const float* __restrict__ bih_f, const float* __restrict__ bhh_f,
    const float* __restrict__ Wih_b, const float* __restrict__ Whh_b,
    const float* __restrict__ bih_b, const float* __restrict__ bhh_b,
    const float* __restrict__ Wfc, const float* __restrict__ bfc,
    float* __restrict__ out) {
  const int tid = threadIdx.x;
  const int q = tid >> 2;  // quad index: chain within wave
  const int j = tid & 3;   // lane within quad: owns h[5j..5j+4]
  const int d = (blockIdx.x >= 256) ? 1 : 0;  // 0=fwd, 1=bwd
  const int blk = blockIdx.x & 255;
  const int b = blk * 16 + q;  // sequence index

  const float* Wih = d ? Wih_b : Wih_f;
  const float* Whh = d ? Whh_b : Whh_f;
  const float* bih = d ? bih_b : bih_f;
  const float* bhh = d ? bhh_b : bhh_f;

  // Load my 5 rows of W_hh (fp32), then pack to fp16 pairs per slot table.
  float w[5][20];
#pragma unroll
  for (int r = 0; r < 5; ++r) {
    const float4* src = reinterpret_cast<const float4*>(Whh + (5 * j + r) * 20);
#pragma unroll
    for (int c4 = 0; c4 < 5; ++c4) {
      float4 v = src[c4];
      w[r][c4 * 4 + 0] = v.x;
      w[r][c4 * 4 + 1] = v.y;
      w[r][c4 * 4 + 2] = v.z;
      w[r][c4 * 4 + 3] = v.w;
    }
  }
  const int c0[10] = {0, 2, 4, 5, 7, 10, 12, 14, 15, 17};
  const int c1[10] = {1, 3, 9, 6, 8, 11, 13, 19, 16, 18};
  half2v wpk[5][10];
#pragma unroll
  for (int r = 0; r < 5; ++r)
#pragma unroll
    for (int s = 0; s < 10; ++s)
      wpk[r][s] = mk_h2(w[r][c0[s]], w[r][c1[s]]);

  float wih[5], bc[5], wfc[5];
#pragma unroll
  for (int m = 0; m < 5; ++m) {
    int hrow = 5 * j + m;
    wih[m] = Wih[hrow];
    bc[m] = bih[hrow] + bhh[hrow];
    wfc[m] = Wfc[(q & 1) * 20 + hrow];  // even b -> W_fc[0:20], odd -> [20:40]
  }

  const float* xrow = x + (size_t)b * TT;
  float h[5] = {0.f, 0.f, 0.f, 0.f, 0.f};
  half2v pka = mk_h2(0.f, 0.f), pkb = pka, pkc = pka;

  // x prefetch: lane j holds 2 of the next 8 x values (mirrored for bwd).
  auto xload = [&](int s8) -> float2 {
    int base = d ? (TT - 2 - s8 - 2 * j) : (s8 + 2 * j);
    float2 v = *reinterpret_cast<const float2*>(xrow + base);
    if (d) {
      float t = v.x; v.x = v.y; v.y = t;
    }
    return v;
  };

  float2 xc = xload(0);
  for (int s8 = 0; s8 < TT; s8 += 8) {
    float2 xn = xc;
    if (s8 + 8 < TT) xn = xload(s8 + 8);
    STEP(0, 0); STEP(0, 1);
    STEP(1, 0); STEP(1, 1);
    STEP(2, 0); STEP(2, 1);
    STEP(3, 0); STEP(3, 1);
    xc = xn;
  }

  // Epilogue. h regs hold S*tanh -> unscale by 1/S folded into the final fma.
  float p = 0.f;
#pragma unroll
  for (int m = 0; m < 5; ++m) p = __builtin_fmaf(wfc[m], h[m], p);
  p += QXOR1_F(p);
  p += QXOR2_F(p);
  float pn = __builtin_bit_cast(
      float, __builtin_amdgcn_ds_swizzle(__builtin_bit_cast(int, p), 0x101F));
  float tot = p + pn;  // sum over the quad pair (40 terms)
  if ((tid & 7) == 0) {
    const float invS = (float)(1.0 / 1.00048828125);
    int oidx = d * (BB / 2) + blk * 8 + (tid >> 3);
    out[oidx] = __builtin_fmaf(tot, invS, bfc[0]);
  }
}

extern "C" void kernel_launch(void* const* d_in, const int* in_sizes, int n_in,
                              void* d_out, int out_size, void* d_ws,
                              size_t ws_size, hipStream_t stream) {
  (void)in_sizes; (void)n_in; (void)d_ws; (void)ws_size; (void)out_size;
  const float* x     = (const float*)d_in[0];
  const float* Wih_f = (const float*)d_in[1];
  const float* Whh_f = (const float*)d_in[2];
  const float* bih_f = (const float*)d_in[3];
  const float* bhh_f = (const float*)d_in[4];
  const float* Wih_b = (const float*)d_in[5];
  const float* Whh_b = (const float*)d_in[6];
  const float* bih_b = (const float*)d_in[7];
  const float* bhh_b = (const float*)d_in[8];
  const float* Wfc   = (const float*)d_in[9];
  const float* bfc   = (const float*)d_in[10];
  float* out = (float*)d_out;

  hipLaunchKernelGGL(rnn_bidir_kernel, dim3(512), dim3(64), 0, stream,
                     x, Wih_f, Whh_f, bih_f, bhh_f,
                     Wih_b, Whh_b, bih_b, bhh_b, Wfc, bfc, out);
}

// Round 3
// 385.385 us; speedup vs baseline: 1.6598x; 1.0568x over previous
//
#include <hip/hip_runtime.h>

// Bidirectional RNN (H=20, input=1), B=4096, T=2048.
// One chain per 8-lane group (8 chains/wave, 1024 waves -> 1 wave on every
// SIMD). Lane r owns rows {r, r+8, 16+r} (phantom zero row for r>=4), full
// k-range -> no cross-lane reduction. Per step: 30 dot2 + 3 tanh; the 10
// packed-h broadcasts go through ds_swizzle (DS pipe) so they don't consume
// VALU issue slots (single wave/SIMD issues at ~4 cyc/instr -> VALU slots are
// the scarce resource). fp16 weights/h with RTZ-bias-corrected pack (as R2).

static constexpr int TT = 2048;   // sequence length
static constexpr int BB = 4096;   // batch

using half2v = decltype(__builtin_amdgcn_cvt_pkrtz(0.0f, 0.0f));

// DPP (ctrl must be literal)
#define QBI(v, CTRL) __builtin_amdgcn_update_dpp(0, (v), (CTRL), 0xF, 0xF, true)
#define QBF(v, CTRL) __builtin_bit_cast(float, QBI(__builtin_bit_cast(int, (v)), (CTRL)))
#define QXOR1_F(v) QBF((v), 0xB1)  // quad_perm [1,0,3,2]

// ds_swizzle bit-mode: src = ((lane & and) | or) ^ xor ; offset[14:10]=xor,
// [9:5]=or, [4:0]=and. Broadcast lane S of each 8-lane group: and=0x18, or=S.
#define BC8(v, S) __builtin_bit_cast(half2v, __builtin_amdgcn_ds_swizzle( \
    __builtin_bit_cast(int, (v)), (((S) << 5) | 0x18)))
#define SWZF(v, OFF) __builtin_bit_cast(float, __builtin_amdgcn_ds_swizzle( \
    __builtin_bit_cast(int, (v)), (OFF)))

#if defined(__has_builtin) && __has_builtin(__builtin_amdgcn_fdot2)
#define FDOT2(a, b, c) __builtin_amdgcn_fdot2((a), (b), (c), false)
#else
#define FDOT2(a, b, c) \
  ((c) + (float)(a)[0] * (float)(b)[0] + (float)(a)[1] * (float)(b)[1])
#endif

__device__ __forceinline__ half2v mk_h2(float a, float b) {
  half2v t{};
  t[0] = a;  // RNE float->fp16
  t[1] = b;
  return t;
}

// tanh with (1+2^-11) output pre-scale (cancels cvt_pkrtz RTZ bias):
//   h = S * (1 - 2/(1 + e^{2a})), S = 1.00048828125. tanh_scaled(0) == 0.
__device__ __forceinline__ float tanh_scaled(float a) {
  float u = __builtin_amdgcn_exp2f(a * 2.8853900817779268f);  // e^{2a}
  float r = __builtin_amdgcn_rcpf(1.0f + u);
  return __builtin_fmaf(-2.0009765625f, r, 1.00048828125f);
}

// One recurrence step; E = compile-time element of the float4 x buffer.
// hb[s] (s<8) = (h[s], h[s+8]) from lane s; hb[8]=(h16,h17) lane0;
// hb[9]=(h18,h19) lane2.
#define STEP(E)                                                             \
  do {                                                                      \
    half2v hb[10];                                                          \
    hb[0] = BC8(pk01, 0); hb[1] = BC8(pk01, 1);                             \
    hb[2] = BC8(pk01, 2); hb[3] = BC8(pk01, 3);                             \
    hb[4] = BC8(pk01, 4); hb[5] = BC8(pk01, 5);                             \
    hb[6] = BC8(pk01, 6); hb[7] = BC8(pk01, 7);                             \
    hb[8] = BC8(pkc, 0);  hb[9] = BC8(pkc, 2);                              \
    float xv = ((E) == 0 ? xq.x : (E) == 1 ? xq.y : (E) == 2 ? xq.z : xq.w);\
    float a0 = __builtin_fmaf(xv, wih[0], bc[0]);                           \
    float a1 = __builtin_fmaf(xv, wih[1], bc[1]);                           \
    float a2 = __builtin_fmaf(xv, wih[2], bc[2]);                           \
    _Pragma("unroll") for (int s = 0; s < 10; ++s) {                        \
      a0 = FDOT2(hb[s], wpk[0][s], a0);                                     \
      a1 = FDOT2(hb[s], wpk[1][s], a1);                                     \
      a2 = FDOT2(hb[s], wpk[2][s], a2);                                     \
    }                                                                       \
    h0 = tanh_scaled(a0);                                                   \
    h1 = tanh_scaled(a1);                                                   \
    h2 = tanh_scaled(a2);                                                   \
    float dd = QXOR1_F(h2);                                                 \
    pk01 = __builtin_amdgcn_cvt_pkrtz(h0, h1);                              \
    pkc  = __builtin_amdgcn_cvt_pkrtz(h2, dd);                              \
  } while (0)

__global__ __launch_bounds__(64, 1) void rnn_bidir_kernel(
    const float* __restrict__ x,
    const float* __restrict__ Wih_f, const float* __restrict__ Whh_f,
    const float* __restrict__ bih_f, const float* __restrict__ bhh_f,
    const float* __restrict__ Wih_b, const float* __restrict__ Whh_b,
    const float* __restrict__ bih_b, const float* __restrict__ bhh_b,
    const float* __restrict__ Wfc, const float* __restrict__ bfc,
    float* __restrict__ out) {
  const int lane = threadIdx.x;
  const int g = lane >> 3;  // chain within wave (0..7)
  const int r = lane & 7;   // row-lane: owns rows r, r+8, 16+r (r<4)
  const int d = (blockIdx.x >= 512) ? 1 : 0;  // 0=fwd, 1=bwd
  const int blk = blockIdx.x & 511;
  const int b = blk * 8 + g;  // sequence index 0..4095

  const float* Wih = d ? Wih_b : Wih_f;
  const float* Whh = d ? Whh_b : Whh_f;
  const float* bih = d ? bih_b : bih_f;
  const float* bhh = d ? bhh_b : bhh_f;

  const bool ph = (r >= 4);  // row2 = 16+r is phantom for r>=4

  // Load my 3 rows of W_hh (fp32), phantom -> zeros.
  float w[3][20];
#pragma unroll
  for (int i = 0; i < 3; ++i) {
    int row = (i == 0) ? r : (i == 1) ? (r + 8) : (16 + r);
    bool valid = (i < 2) || !ph;
    const float4* src = reinterpret_cast<const float4*>(Whh + row * 20);
#pragma unroll
    for (int c4 = 0; c4 < 5; ++c4) {
      float4 v = valid ? src[c4] : float4{0.f, 0.f, 0.f, 0.f};
      w[i][c4 * 4 + 0] = v.x;
      w[i][c4 * 4 + 1] = v.y;
      w[i][c4 * 4 + 2] = v.z;
      w[i][c4 * 4 + 3] = v.w;
    }
  }
  // Pack: slot s<8 -> (k=s, k=s+8); slot 8 -> (16,17); slot 9 -> (18,19).
  half2v wpk[3][10];
#pragma unroll
  for (int i = 0; i < 3; ++i) {
#pragma unroll
    for (int s = 0; s < 8; ++s) wpk[i][s] = mk_h2(w[i][s], w[i][s + 8]);
    wpk[i][8] = mk_h2(w[i][16], w[i][17]);
    wpk[i][9] = mk_h2(w[i][18], w[i][19]);
  }

  float wih[3], bc[3], wfc[3];
#pragma unroll
  for (int i = 0; i < 3; ++i) {
    int row = (i == 0) ? r : (i == 1) ? (r + 8) : (16 + r);
    bool valid = (i < 2) || !ph;
    wih[i] = valid ? Wih[row] : 0.f;
    bc[i] = valid ? (bih[row] + bhh[row]) : 0.f;
    // even chain -> W_fc[0:20], odd chain -> W_fc[20:40]
    wfc[i] = valid ? Wfc[(g & 1) * 20 + row] : 0.f;
  }

  const float* xrow = x + (size_t)b * TT;
  float h0 = 0.f, h1 = 0.f, h2 = 0.f;
  half2v pk01 = mk_h2(0.f, 0.f), pkc = pk01;

  // All 8 lanes of a chain load the same float4 (4 steps); bwd mirrored.
  auto xload = [&](int s4) -> float4 {
    int base = d ? (TT - 4 - s4) : s4;
    float4 v = *reinterpret_cast<const float4*>(xrow + base);
    if (d) {
      float t = v.x; v.x = v.w; v.w = t;
      t = v.y; v.y = v.z; v.z = t;
    }
    return v;
  };

  float4 xq = xload(0);
  for (int s4 = 0; s4 < TT; s4 += 4) {
    float4 xn = xq;
    if (s4 + 4 < TT) xn = xload(s4 + 4);  // prefetch next 4 steps
    STEP(0); STEP(1); STEP(2); STEP(3);
    xq = xn;
  }

  // Epilogue: h regs hold S*tanh -> unscale folded into final fma.
  // Sum over 16 lanes (chain pair g even/odd) via xor butterfly.
  float p = wfc[0] * h0;
  p = __builtin_fmaf(wfc[1], h1, p);
  p = __builtin_fmaf(wfc[2], h2, p);
  p += SWZF(p, 0x041F);  // xor 1
  p += SWZF(p, 0x081F);  // xor 2
  p += SWZF(p, 0x101F);  // xor 4
  p += SWZF(p, 0x201F);  // xor 8 -> sum over 16-lane group (40 terms)
  if ((lane & 15) == 0) {
    const float invS = (float)(1.0 / 1.00048828125);
    int oidx = d * (BB / 2) + blk * 4 + (g >> 1);
    out[oidx] = __builtin_fmaf(p, invS, bfc[0]);
  }
}

extern "C" void kernel_launch(void* const* d_in, const int* in_sizes, int n_in,
                              void* d_out, int out_size, void* d_ws,
                              size_t ws_size, hipStream_t stream) {
  (void)in_sizes; (void)n_in; (void)d_ws; (void)ws_size; (void)out_size;
  const float* x     = (const float*)d_in[0];
  const float* Wih_f = (const float*)d_in[1];
  const float* Whh_f = (const float*)d_in[2];
  const float* bih_f = (const float*)d_in[3];
  const float* bhh_f = (const float*)d_in[4];
  const float* Wih_b = (const float*)d_in[5];
  const float* Whh_b = (const float*)d_in[6];
  const float* bih_b = (const float*)d_in[7];
  const float* bhh_b = (const float*)d_in[8];
  const float* Wfc   = (const float*)d_in[9];
  const float* bfc   = (const float*)d_in[10];
  float* out = (float*)d_out;

  // 512 fwd blocks + 512 bwd blocks, 1 wave each (8 chains/wave).
  hipLaunchKernelGGL(rnn_bidir_kernel, dim3(1024), dim3(64), 0, stream,
                     x, Wih_f, Whh_f, bih_f, bhh_f,
                     Wih_b, Whh_b, bih_b, bhh_b, Wfc, bfc, out);
}

// Round 4
// 288.441 us; speedup vs baseline: 2.2177x; 1.3361x over previous
//
#include <hip/hip_runtime.h>

// Bidirectional RNN (H=20, input=1), B=4096, T=2048.
// One chain per 8-lane group, 8 chains/wave, 1024 waves (1 per SIMD).
// Lane r (0..7) owns rows {r, r+8, 16+(r&3)} (rows 16..19 duplicated in both
// quads so their packed pairs are broadcastable with one quad_perm).
// ALL h broadcasts are DPP (VALU pipe) -- zero DS ops in the inner loop:
//   pair (s, s+4): t = quad_perm[s,s,s,s]; m = row_half_mirror(t) (0x141);
//   per-lane weight-slot permutation (quad1 swaps wA/wB) avoids any select.
// fp16 dot2 weights/h with RTZ-bias-corrected pack (as R2/R3); tanh input
// scale 2/ln2 folded into weights+bias so tanh = exp2,add,rcp,fma (4 ops).

static constexpr int TT = 2048;   // sequence length
static constexpr int BB = 4096;   // batch

using half2v = decltype(__builtin_amdgcn_cvt_pkrtz(0.0f, 0.0f));

// DPP helpers (ctrl must be a literal).
#define DPPI(v, CTRL) __builtin_amdgcn_update_dpp(0, (v), (CTRL), 0xF, 0xF, true)
#define DPPF(v, CTRL) __builtin_bit_cast(float, DPPI(__builtin_bit_cast(int, (v)), (CTRL)))
#define DPPH(v, CTRL) __builtin_bit_cast(half2v, DPPI(__builtin_bit_cast(int, (v)), (CTRL)))
#define QXOR1_F(v) DPPF((v), 0xB1)   // quad_perm [1,0,3,2]
#define HMIR(v) DPPH((v), 0x141)     // row_half_mirror (within 8 lanes)

#define SWZF(v, OFF) __builtin_bit_cast(float, __builtin_amdgcn_ds_swizzle( \
    __builtin_bit_cast(int, (v)), (OFF)))

#if defined(__has_builtin) && __has_builtin(__builtin_amdgcn_fdot2)
#define FDOT2(a, b, c) __builtin_amdgcn_fdot2((a), (b), (c), false)
#else
#define FDOT2(a, b, c) \
  ((c) + (float)(a)[0] * (float)(b)[0] + (float)(a)[1] * (float)(b)[1])
#endif

__device__ __forceinline__ half2v mk_h2(float a, float b) {
  half2v t{};
  t[0] = a;  // RNE float->fp16
  t[1] = b;
  return t;
}

// Inputs pre-scaled by SC = 2/ln2, so u = exp2(acc) = e^{2a}.
// h = S * (1 - 2/(1+u)), S = 1+2^-11 cancels cvt_pkrtz RTZ bias.
// tanh4(0) == 0 exactly; +/-inf safe.
__device__ __forceinline__ float tanh4(float acc) {
  float u = __builtin_amdgcn_exp2f(acc);
  float r = __builtin_amdgcn_rcpf(1.0f + u);
  return __builtin_fmaf(-2.0009765625f, r, 1.00048828125f);
}

// One step; E = compile-time element index of the float4 x buffer.
// Slot s (s<8) = packed (h[s], h[s+8]); slot 8 = (h16,h17); slot 9 = (h18,h19).
#define STEP(E)                                                             \
  do {                                                                      \
    half2v t0 = DPPH(pk01, 0x00), m0 = HMIR(t0);                            \
    half2v t1 = DPPH(pk01, 0x55), m1 = HMIR(t1);                            \
    half2v t2 = DPPH(pk01, 0xAA), m2 = HMIR(t2);                            \
    half2v t3 = DPPH(pk01, 0xFF), m3 = HMIR(t3);                            \
    half2v t8 = DPPH(pkc, 0x00), t9 = DPPH(pkc, 0xAA);                      \
    float xv = ((E) == 0 ? xq.x : (E) == 1 ? xq.y : (E) == 2 ? xq.z : xq.w);\
    float a0 = __builtin_fmaf(xv, wih[0], bc[0]);                           \
    float a1 = __builtin_fmaf(xv, wih[1], bc[1]);                           \
    float a2 = __builtin_fmaf(xv, wih[2], bc[2]);                           \
    a0 = FDOT2(t0, wA[0][0], a0); a1 = FDOT2(t0, wA[1][0], a1);             \
    a2 = FDOT2(t0, wA[2][0], a2);                                           \
    a0 = FDOT2(m0, wB[0][0], a0); a1 = FDOT2(m0, wB[1][0], a1);             \
    a2 = FDOT2(m0, wB[2][0], a2);                                           \
    a0 = FDOT2(t1, wA[0][1], a0); a1 = FDOT2(t1, wA[1][1], a1);             \
    a2 = FDOT2(t1, wA[2][1], a2);                                           \
    a0 = FDOT2(m1, wB[0][1], a0); a1 = FDOT2(m1, wB[1][1], a1);             \
    a2 = FDOT2(m1, wB[2][1], a2);                                           \
    a0 = FDOT2(t2, wA[0][2], a0); a1 = FDOT2(t2, wA[1][2], a1);             \
    a2 = FDOT2(t2, wA[2][2], a2);                                           \
    a0 = FDOT2(m2, wB[0][2], a0); a1 = FDOT2(m2, wB[1][2], a1);             \
    a2 = FDOT2(m2, wB[2][2], a2);                                           \
    a0 = FDOT2(t3, wA[0][3], a0); a1 = FDOT2(t3, wA[1][3], a1);             \
    a2 = FDOT2(t3, wA[2][3], a2);                                           \
    a0 = FDOT2(m3, wB[0][3], a0); a1 = FDOT2(m3, wB[1][3], a1);             \
    a2 = FDOT2(m3, wB[2][3], a2);                                           \
    a0 = FDOT2(t8, w8[0], a0); a1 = FDOT2(t8, w8[1], a1);                   \
    a2 = FDOT2(t8, w8[2], a2);                                              \
    a0 = FDOT2(t9, w9[0], a0); a1 = FDOT2(t9, w9[1], a1);                   \
    a2 = FDOT2(t9, w9[2], a2);                                              \
    h0 = tanh4(a0); h1 = tanh4(a1); h2 = tanh4(a2);                         \
    float dd = QXOR1_F(h2);                                                 \
    pk01 = __builtin_amdgcn_cvt_pkrtz(h0, h1);                              \
    pkc  = __builtin_amdgcn_cvt_pkrtz(h2, dd);                              \
  } while (0)

__global__ __launch_bounds__(64, 1) void rnn_bidir_kernel(
    const float* __restrict__ x,
    const float* __restrict__ Wih_f, const float* __restrict__ Whh_f,
    const float* __restrict__ bih_f, const float* __restrict__ bhh_f,
    const float* __restrict__ Wih_b, const float* __restrict__ Whh_b,
    const float* __restrict__ bih_b, const float* __restrict__ bhh_b,
    const float* __restrict__ Wfc, const float* __restrict__ bfc,
    float* __restrict__ out) {
  const int lane = threadIdx.x;
  const int g = lane >> 3;            // chain within wave (0..7)
  const int r = lane & 7;             // row-lane
  const int qhi = (lane >> 2) & 1;    // which quad within the 8-lane group
  const int d = (blockIdx.x >= 512) ? 1 : 0;  // 0=fwd, 1=bwd
  const int blk = blockIdx.x & 511;
  const int b = blk * 8 + g;          // sequence index 0..4095

  const float* Wih = d ? Wih_b : Wih_f;
  const float* Whh = d ? Whh_b : Whh_f;
  const float* bih = d ? bih_b : bih_f;
  const float* bhh = d ? bhh_b : bhh_f;

  const float SC = 2.8853900817779268f;  // 2/ln2: folded tanh input scale

  // Rows owned by this lane (rows 16..19 duplicated across both quads).
  const int row[3] = {r, r + 8, 16 + (r & 3)};

  // Load 3 rows of W_hh (fp32), pack to scaled fp16 slot pairs.
  float w[3][20];
#pragma unroll
  for (int i = 0; i < 3; ++i) {
    const float4* src = reinterpret_cast<const float4*>(Whh + row[i] * 20);
#pragma unroll
    for (int c4 = 0; c4 < 5; ++c4) {
      float4 v = src[c4];
      w[i][c4 * 4 + 0] = v.x;
      w[i][c4 * 4 + 1] = v.y;
      w[i][c4 * 4 + 2] = v.z;
      w[i][c4 * 4 + 3] = v.w;
    }
  }
  half2v wpk[3][10];
#pragma unroll
  for (int i = 0; i < 3; ++i) {
#pragma unroll
    for (int s = 0; s < 8; ++s)
      wpk[i][s] = mk_h2(SC * w[i][s], SC * w[i][s + 8]);
    wpk[i][8] = mk_h2(SC * w[i][16], SC * w[i][17]);
    wpk[i][9] = mk_h2(SC * w[i][18], SC * w[i][19]);
  }
  // Weight-slot permutation so DPP t/m pairs feed dot2 with no selects:
  // quad0: t_s -> slot s,  m_s -> slot s+4 ; quad1: swapped.
  half2v wA[3][4], wB[3][4], w8[3], w9[3];
#pragma unroll
  for (int i = 0; i < 3; ++i) {
#pragma unroll
    for (int s = 0; s < 4; ++s) {
      wA[i][s] = qhi ? wpk[i][s + 4] : wpk[i][s];
      wB[i][s] = qhi ? wpk[i][s] : wpk[i][s + 4];
    }
    w8[i] = wpk[i][8];
    w9[i] = wpk[i][9];
  }

  float wih[3], bc[3], wfc[3];
#pragma unroll
  for (int i = 0; i < 3; ++i) {
    wih[i] = SC * Wih[row[i]];
    bc[i] = SC * (bih[row[i]] + bhh[row[i]]);
    // even chain -> W_fc[0:20], odd -> W_fc[20:40]; duplicated row2 counted
    // only on quad0.
    float f = Wfc[(g & 1) * 20 + row[i]];
    wfc[i] = (i == 2 && qhi) ? 0.f : f;
  }

  const float* xrow = x + (size_t)b * TT;
  float h0 = 0.f, h1 = 0.f, h2 = 0.f;
  half2v pk01 = mk_h2(0.f, 0.f), pkc = pk01;

  // All 8 lanes of a chain load the same float4 (4 steps); bwd mirrored.
  auto xload = [&](int s4) -> float4 {
    int base = d ? (TT - 4 - s4) : s4;
    float4 v = *reinterpret_cast<const float4*>(xrow + base);
    if (d) {
      float t = v.x; v.x = v.w; v.w = t;
      t = v.y; v.y = v.z; v.z = t;
    }
    return v;
  };

  float4 xq = xload(0);
  for (int s4 = 0; s4 < TT; s4 += 4) {
    float4 xn = xq;
    if (s4 + 4 < TT) xn = xload(s4 + 4);  // prefetch next 4 steps
    STEP(0); STEP(1); STEP(2); STEP(3);
    xq = xn;
  }

  // Epilogue: h regs hold S*tanh -> unscale folded into final fma.
  float p = wfc[0] * h0;
  p = __builtin_fmaf(wfc[1], h1, p);
  p = __builtin_fmaf(wfc[2], h2, p);
  p += SWZF(p, 0x041F);  // xor 1
  p += SWZF(p, 0x081F);  // xor 2
  p += SWZF(p, 0x101F);  // xor 4
  p += SWZF(p, 0x201F);  // xor 8 -> sum over 16-lane chain pair (40 terms)
  if ((lane & 15) == 0) {
    const float invS = (float)(1.0 / 1.00048828125);
    int oidx = d * (BB / 2) + blk * 4 + (g >> 1);
    out[oidx] = __builtin_fmaf(p, invS, bfc[0]);
  }
}

extern "C" void kernel_launch(void* const* d_in, const int* in_sizes, int n_in,
                              void* d_out, int out_size, void* d_ws,
                              size_t ws_size, hipStream_t stream) {
  (void)in_sizes; (void)n_in; (void)d_ws; (void)ws_size; (void)out_size;
  const float* x     = (const float*)d_in[0];
  const float* Wih_f = (const float*)d_in[1];
  const float* Whh_f = (const float*)d_in[2];
  const float* bih_f = (const float*)d_in[3];
  const float* bhh_f = (const float*)d_in[4];
  const float* Wih_b = (const float*)d_in[5];
  const float* Whh_b = (const float*)d_in[6];
  const float* bih_b = (const float*)d_in[7];
  const float* bhh_b = (const float*)d_in[8];
  const float* Wfc   = (const float*)d_in[9];
  const float* bfc   = (const float*)d_in[10];
  float* out = (float*)d_out;

  // 512 fwd blocks + 512 bwd blocks, 1 wave each (8 chains/wave).
  hipLaunchKernelGGL(rnn_bidir_kernel, dim3(1024), dim3(64), 0, stream,
                     x, Wih_f, Whh_f, bih_f, bhh_f,
                     Wih_b, Whh_b, bih_b, bhh_b, Wfc, bfc, out);
}

// Round 5
// 280.557 us; speedup vs baseline: 2.2800x; 1.0281x over previous
//
#include <hip/hip_runtime.h>

// Bidirectional RNN (H=20, input=1), B=4096, T=2048.
// One chain per 8-lane group, 8 chains/wave, 1024 waves (1/SIMD).
// Lane r owns rows {r, r+8} full-k, plus a HALF (k-split) of shared row
// 16+min(r,7-r) (partner lane 7-r owns the other half; combined via
// row_half_mirror DPP). State tracked as r' = S/(1+e^{2a}) (h = 1-2r'/S is
// affine in r' -> W*1 folded into bias exactly from the quantized weights,
// -2/S folded into fp16 weights). tanh = exp2+add+rcp (3 ops). All
// broadcasts are DPP (VALU pipe); zero DS in the inner loop. fp16 dot2
// with RTZ-bias-corrected pack (S = 1+2^-11 pre-scale).

static constexpr int TT = 2048;   // sequence length
static constexpr int BB = 4096;   // batch

using half2v = decltype(__builtin_amdgcn_cvt_pkrtz(0.0f, 0.0f));

// DPP helpers (ctrl must be a literal).
#define DPPI(v, CTRL) __builtin_amdgcn_update_dpp(0, (v), (CTRL), 0xF, 0xF, true)
#define DPPF(v, CTRL) __builtin_bit_cast(float, DPPI(__builtin_bit_cast(int, (v)), (CTRL)))
#define DPPH(v, CTRL) __builtin_bit_cast(half2v, DPPI(__builtin_bit_cast(int, (v)), (CTRL)))
#define QXOR1_F(v) DPPF((v), 0xB1)   // quad_perm [1,0,3,2]
#define HMIRH(v) DPPH((v), 0x141)    // row_half_mirror: lane l <- 7-l (in 8)
#define HMIRF(v) DPPF((v), 0x141)

#define SWZF(v, OFF) __builtin_bit_cast(float, __builtin_amdgcn_ds_swizzle( \
    __builtin_bit_cast(int, (v)), (OFF)))

#if defined(__has_builtin) && __has_builtin(__builtin_amdgcn_fdot2)
#define FDOT2(a, b, c) __builtin_amdgcn_fdot2((a), (b), (c), false)
#else
#define FDOT2(a, b, c) \
  ((c) + (float)(a)[0] * (float)(b)[0] + (float)(a)[1] * (float)(b)[1])
#endif

__device__ __forceinline__ float qf16(float v) {  // RNE f32->fp16->f32
  _Float16 t = (_Float16)v;
  return (float)t;
}
__device__ __forceinline__ half2v mk_h2(float a, float b) {
  half2v t{};
  t[0] = a;  // RNE
  t[1] = b;
  return t;
}

// Constants:
//  SC  = 2/ln2 (tanh input scale, folded into weights/bias)
//  S   = 1+2^-11 (RTZ pack bias correction)   C = 1/S
//  LGC = log2(1/S) (folded into bias so exp2(acc) = C*e^{2a})
//  K2S = 2*SC/S (weight quantization scale; stored Wq = fp16(-K2S*W))
#define SCc  2.8853900817779268f
#define Sc   1.00048828125f
#define CCc  0.9995119571685791f
#define LGCc (-7.0425384e-4f)
#define K2Sc 5.7675648927297470f
#define M2Sc (-1.9990239143371582f)

// One step; E = compile-time element of the float4 x buffer.
// Slots: s (0..7) = packed (r'[s], r'[s+8]); rA/rB = tail pairs:
//  quad0: rA=(16,17), rB=(19,18); quad1: rA=(19,18), rB=(16,17)
//  (order absorbed into per-lane weight packs).
#define STEP(E)                                                             \
  do {                                                                      \
    half2v t0 = DPPH(pk01, 0x00), m0 = HMIRH(t0);                           \
    half2v t1 = DPPH(pk01, 0x55), m1 = HMIRH(t1);                           \
    half2v t2 = DPPH(pk01, 0xAA), m2 = HMIRH(t2);                           \
    half2v t3 = DPPH(pk01, 0xFF), m3 = HMIRH(t3);                           \
    half2v rA = DPPH(pkc, 0x00),  rB = HMIRH(rA);                           \
    float xv = ((E) == 0 ? xq.x : (E) == 1 ? xq.y : (E) == 2 ? xq.z : xq.w);\
    float a0a = __builtin_fmaf(xv, wihv[0], bcv[0]);                        \
    float a1a = __builtin_fmaf(xv, wihv[1], bcv[1]);                        \
    float a2p = __builtin_fmaf(xv, wihv[2], bcv[2]);                        \
    a0a = FDOT2(t0, wAq[0][0], a0a);                                        \
    a1a = FDOT2(t0, wAq[1][0], a1a);                                        \
    a2p = FDOT2(t0, w2q[0], a2p);                                           \
    float a0b = FDOT2(m0, wBq[0][0], 0.0f);                                 \
    float a1b = FDOT2(m0, wBq[1][0], 0.0f);                                 \
    a0a = FDOT2(t1, wAq[0][1], a0a);                                        \
    a1a = FDOT2(t1, wAq[1][1], a1a);                                        \
    a2p = FDOT2(t1, w2q[1], a2p);                                           \
    a0b = FDOT2(m1, wBq[0][1], a0b);                                        \
    a1b = FDOT2(m1, wBq[1][1], a1b);                                        \
    a0a = FDOT2(t2, wAq[0][2], a0a);                                        \
    a1a = FDOT2(t2, wAq[1][2], a1a);                                        \
    a2p = FDOT2(t2, w2q[2], a2p);                                           \
    a0b = FDOT2(m2, wBq[0][2], a0b);                                        \
    a1b = FDOT2(m2, wBq[1][2], a1b);                                        \
    a0a = FDOT2(t3, wAq[0][3], a0a);                                        \
    a1a = FDOT2(t3, wAq[1][3], a1a);                                        \
    a2p = FDOT2(t3, w2q[3], a2p);                                           \
    a0b = FDOT2(m3, wBq[0][3], a0b);                                        \
    a1b = FDOT2(m3, wBq[1][3], a1b);                                        \
    a0a = FDOT2(rA, wA8[0], a0a);                                           \
    a1a = FDOT2(rA, wA8[1], a1a);                                           \
    a2p = FDOT2(rA, w2q[4], a2p);                                           \
    a0b = FDOT2(rB, wB9[0], a0b);                                           \
    a1b = FDOT2(rB, wB9[1], a1b);                                           \
    float a0 = a0a + a0b;                                                   \
    float a1 = a1a + a1b;                                                   \
    float a2 = a2p + HMIRF(a2p);                                            \
    float u0 = __builtin_amdgcn_exp2f(a0);                                  \
    float u1 = __builtin_amdgcn_exp2f(a1);                                  \
    float u2 = __builtin_amdgcn_exp2f(a2);                                  \
    r0v = __builtin_amdgcn_rcpf(u0 + CCc);                                  \
    r1v = __builtin_amdgcn_rcpf(u1 + CCc);                                  \
    r2v = __builtin_amdgcn_rcpf(u2 + CCc);                                  \
    float dd = QXOR1_F(r2v);                                                \
    pk01 = __builtin_amdgcn_cvt_pkrtz(r0v, r1v);                            \
    pkc  = __builtin_amdgcn_cvt_pkrtz(r2v, dd);                             \
  } while (0)

__global__ __launch_bounds__(64, 1) void rnn_bidir_kernel(
    const float* __restrict__ x,
    const float* __restrict__ Wih_f, const float* __restrict__ Whh_f,
    const float* __restrict__ bih_f, const float* __restrict__ bhh_f,
    const float* __restrict__ Wih_b, const float* __restrict__ Whh_b,
    const float* __restrict__ bih_b, const float* __restrict__ bhh_b,
    const float* __restrict__ Wfc, const float* __restrict__ bfc,
    float* __restrict__ out) {
  const int lane = threadIdx.x;
  const int g = lane >> 3;            // chain within wave (0..7)
  const int r = lane & 7;             // row-lane
  const int qhi = (lane >> 2) & 1;    // quad within the 8-lane group
  const int d = (blockIdx.x >= 512) ? 1 : 0;  // 0=fwd, 1=bwd
  const int blk = blockIdx.x & 511;
  const int b = blk * 8 + g;          // sequence index

  const float* Wih = d ? Wih_b : Wih_f;
  const float* Whh = d ? Whh_b : Whh_f;
  const float* bih = d ? bih_b : bih_f;
  const float* bhh = d ? bhh_b : bhh_f;

  const int r2row = 16 + ((r < 4) ? r : (7 - r));  // shared row (k-split)
  const int row01[2] = {r, r + 8};

  // Load the 3 fp32 rows.
  float w[3][20];
#pragma unroll
  for (int i = 0; i < 3; ++i) {
    int row = (i < 2) ? row01[i] : r2row;
    const float4* src = reinterpret_cast<const float4*>(Whh + row * 20);
#pragma unroll
    for (int c4 = 0; c4 < 5; ++c4) {
      float4 v = src[c4];
      w[i][c4 * 4 + 0] = v.x;
      w[i][c4 * 4 + 1] = v.y;
      w[i][c4 * 4 + 2] = v.z;
      w[i][c4 * 4 + 3] = v.w;
    }
  }

  // Quantized weight packs (Wq = fp16(-K2S*W)) + exact W*1 compensation
  // K_row = -(S/2) * sum_k Wq[k] (sum of the dequantized stored values).
  half2v wAq[2][4], wBq[2][4], wA8[2], wB9[2], w2q[5];
  float Krow[3];
#pragma unroll
  for (int i = 0; i < 2; ++i) {
    float sq = 0.f;
#pragma unroll
    for (int k = 0; k < 20; ++k) sq += qf16(-K2Sc * w[i][k]);
    Krow[i] = -(Sc * 0.5f) * sq;
#pragma unroll
    for (int s = 0; s < 4; ++s) {
      int sA = qhi ? s + 4 : s;   // t_s delivers slot sA on my quad
      int sB = qhi ? s : s + 4;   // m_s delivers slot sB
      wAq[i][s] = mk_h2(-K2Sc * w[i][sA], -K2Sc * w[i][sA + 8]);
      wBq[i][s] = mk_h2(-K2Sc * w[i][sB], -K2Sc * w[i][sB + 8]);
    }
    wA8[i] = qhi ? mk_h2(-K2Sc * w[i][19], -K2Sc * w[i][18])
                 : mk_h2(-K2Sc * w[i][16], -K2Sc * w[i][17]);
    wB9[i] = qhi ? mk_h2(-K2Sc * w[i][16], -K2Sc * w[i][17])
                 : mk_h2(-K2Sc * w[i][19], -K2Sc * w[i][18]);
  }
  {
    float sq = 0.f;
#pragma unroll
    for (int k = 0; k < 20; ++k) sq += qf16(-K2Sc * w[2][k]);
    Krow[2] = -(Sc * 0.5f) * sq;
#pragma unroll
    for (int s = 0; s < 4; ++s) {
      int k0 = qhi ? 4 + s : s;   // my quad's k-half: q0 {0..3}, q1 {4..7}
      w2q[s] = mk_h2(-K2Sc * w[2][k0], -K2Sc * w[2][k0 + 8]);
    }
    w2q[4] = qhi ? mk_h2(-K2Sc * w[2][19], -K2Sc * w[2][18])
                 : mk_h2(-K2Sc * w[2][16], -K2Sc * w[2][17]);
  }

  // Biases (SC-scaled, + K_row compensation + LGC), input weights, fc weights.
  // Row2: only the r<4 partner carries bias/x (other half starts at 0).
  float wihv[3], bcv[3], wfc[3];
#pragma unroll
  for (int i = 0; i < 2; ++i) {
    int row = row01[i];
    wihv[i] = SCc * Wih[row];
    bcv[i] = SCc * (bih[row] + bhh[row]) + Krow[i] + LGCc;
    wfc[i] = Wfc[(g & 1) * 20 + row];
  }
  if (r < 4) {
    wihv[2] = SCc * Wih[r2row];
    bcv[2] = SCc * (bih[r2row] + bhh[r2row]) + Krow[2] + LGCc;
    wfc[2] = Wfc[(g & 1) * 20 + r2row];
  } else {
    wihv[2] = 0.f;
    bcv[2] = 0.f;
    wfc[2] = 0.f;  // duplicated row: counted by the r<4 partner only
  }

  const float* xrow = x + (size_t)b * TT;
  // h = 0  <=>  r' = S/2; fp16(S/2) == 0.5 exactly.
  half2v pk01 = mk_h2(0.5f, 0.5f), pkc = pk01;
  float r0v = 0.5f, r1v = 0.5f, r2v = 0.5f;

  auto xload = [&](int s4) -> float4 {
    int base = d ? (TT - 4 - s4) : s4;
    float4 v = *reinterpret_cast<const float4*>(xrow + base);
    if (d) {
      float t = v.x; v.x = v.w; v.w = t;
      t = v.y; v.y = v.z; v.z = t;
    }
    return v;
  };

  float4 xq = xload(0);
  for (int s4 = 0; s4 < TT; s4 += 4) {
    float4 xn = xq;
    if (s4 + 4 < TT) xn = xload(s4 + 4);  // prefetch next 4 steps
    STEP(0); STEP(1); STEP(2); STEP(3);
    xq = xn;
  }

  // Epilogue: h_i = 1 - (2/S) * r'_i (true scale; no global unscale needed).
  float h0 = __builtin_fmaf(r0v, M2Sc, 1.0f);
  float h1 = __builtin_fmaf(r1v, M2Sc, 1.0f);
  float h2 = __builtin_fmaf(r2v, M2Sc, 1.0f);
  float p = wfc[0] * h0;
  p = __builtin_fmaf(wfc[1], h1, p);
  p = __builtin_fmaf(wfc[2], h2, p);
  p += SWZF(p, 0x041F);  // xor 1
  p += SWZF(p, 0x081F);  // xor 2
  p += SWZF(p, 0x101F);  // xor 4
  p += SWZF(p, 0x201F);  // xor 8 -> sum over the 16-lane chain pair
  if ((lane & 15) == 0) {
    int oidx = d * (BB / 2) + blk * 4 + (g >> 1);
    out[oidx] = p + bfc[0];
  }
}

extern "C" void kernel_launch(void* const* d_in, const int* in_sizes, int n_in,
                              void* d_out, int out_size, void* d_ws,
                              size_t ws_size, hipStream_t stream) {
  (void)in_sizes; (void)n_in; (void)d_ws; (void)ws_size; (void)out_size;
  const float* x     = (const float*)d_in[0];
  const float* Wih_f = (const float*)d_in[1];
  const float* Whh_f = (const float*)d_in[2];
  const float* bih_f = (const float*)d_in[3];
  const float* bhh_f = (const float*)d_in[4];
  const float* Wih_b = (const float*)d_in[5];
  const float* Whh_b = (const float*)d_in[6];
  const float* bih_b = (const float*)d_in[7];
  const float* bhh_b = (const float*)d_in[8];
  const float* Wfc   = (const float*)d_in[9];
  const float* bfc   = (const float*)d_in[10];
  float* out = (float*)d_out;

  // 512 fwd blocks + 512 bwd blocks, 1 wave each (8 chains/wave).
  hipLaunchKernelGGL(rnn_bidir_kernel, dim3(1024), dim3(64), 0, stream,
                     x, Wih_f, Whh_f, bih_f, bhh_f,
                     Wih_b, Whh_b, bih_b, bhh_b, Wfc, bfc, out);
}